// Round 5
// baseline (803.230 us; speedup 1.0000x reference)
//
#include <hip/hip_runtime.h>
#include <stdint.h>

typedef __bf16   bf16x8 __attribute__((ext_vector_type(8)));
typedef float    f32x4  __attribute__((ext_vector_type(4)));
typedef uint32_t u32x4  __attribute__((ext_vector_type(4)));
typedef uint32_t u32x2  __attribute__((ext_vector_type(2)));
typedef unsigned short u16x8 __attribute__((ext_vector_type(8)));

#define L_SEQ 8192
#define DIM   768
#define DROW  8768     // dupG row length in dwords (zero-padded tail)
// dupG[d][i] = ( k[8223-i] in lo16, k[8222-i] in hi16 ), scaled by 1/16384.
// k[s]=0 for s<0 or s>8191  ->  dupG zero for i<31 and i>=8224.

// Workspace layout (bytes):
//   dupG u32  [768][8768]    @ 0            size 26,935,296
//   uT   bf16 [768][8][8192] @ 26,935,296   size 100,663,296
//   yT   bf16 [768][8][8192] @ 127,598,592  size 100,663,296

// ---------------- filter MLP -> dupG pairs (pad fused) --------------------
// grid (256, 4): blockIdx.x = s-chunk, blockIdx.y = dc-group (3 chunks each).
// Inner loops 4-wide over outputs: f32x4 LDS reads -> 4x fewer LDS instrs.
__global__ __launch_bounds__(256) void filter_kernel(
    const float* __restrict__ w_in, const float* __restrict__ b_in,
    const float* __restrict__ freq_in,
    const float* __restrict__ w_h0, const float* __restrict__ b_h0,
    const float* __restrict__ freq_h0,
    const float* __restrict__ w_h1, const float* __restrict__ b_h1,
    const float* __restrict__ freq_h1,
    const float* __restrict__ w_out,
    uint32_t* __restrict__ dupG)
{
  __shared__ float h1[33][65];
  __shared__ float h2[33][65];
  __shared__ unsigned short kv[33][64];
  __shared__ float wch[64][64];

  const int c = blockIdx.x;               // 0..255
  const int dcg = blockIdx.y;             // 0..3
  const int sbase = c << 5;
  const int tid = threadIdx.x;

  // ---- fused pad: zero dupG pad regions (i<31, i>=8224), re-poisoned ----
  {
    int glob = (c << 2) | dcg;            // 0..1023
    int base = glob * 432;                // 1024*432 >= 768*575
    for (int k = base + tid; k < base + 432; k += 256) {
      if (k < 768 * 575) {
        int dd = k / 575, r = k - dd * 575;
        int i = (r < 31) ? r : 8224 + (r - 31);
        dupG[(size_t)dd * DROW + i] = 0u;
      }
    }
  }

  // layer 1 (EMB=3 features)
  for (int p = tid; p < 33 * 64; p += 256) {
    int j = p >> 6, n = p & 63;
    int s = sbase - 1 + j;
    float t  = s * (1.0f / 8191.0f);
    float ph = s * (float)(6.283185307179586 * 1e-4 / 8192.0);
    float a = t * w_in[n] + cosf(ph) * w_in[64 + n] + (-sinf(ph)) * w_in[128 + n] + b_in[n];
    h1[j][n] = sinf(freq_in[n] * a);
  }
  for (int p = tid; p < 64 * 64; p += 256) wch[p >> 6][p & 63] = w_h0[p];
  __syncthreads();
  // layer 2: 4-wide
  for (int p = tid; p < 528; p += 256) {
    int j = p >> 4, n4 = (p & 15) << 2;
    f32x4 a = *(const f32x4*)&b_h0[n4];
    for (int r = 0; r < 64; ++r) {
      f32x4 wv = *(const f32x4*)&wch[r][n4];
      a += h1[j][r] * wv;
    }
    f32x4 f = *(const f32x4*)&freq_h0[n4];
    h2[j][n4 + 0] = sinf(f[0] * a[0]);
    h2[j][n4 + 1] = sinf(f[1] * a[1]);
    h2[j][n4 + 2] = sinf(f[2] * a[2]);
    h2[j][n4 + 3] = sinf(f[3] * a[3]);
  }
  __syncthreads();
  for (int p = tid; p < 64 * 64; p += 256) wch[p >> 6][p & 63] = w_h1[p];
  __syncthreads();
  // layer 3: 4-wide
  for (int p = tid; p < 528; p += 256) {
    int j = p >> 4, n4 = (p & 15) << 2;
    f32x4 a = *(const f32x4*)&b_h1[n4];
    for (int r = 0; r < 64; ++r) {
      f32x4 wv = *(const f32x4*)&wch[r][n4];
      a += h2[j][r] * wv;
    }
    f32x4 f = *(const f32x4*)&freq_h1[n4];
    h1[j][n4 + 0] = sinf(f[0] * a[0]);
    h1[j][n4 + 1] = sinf(f[1] * a[1]);
    h1[j][n4 + 2] = sinf(f[2] * a[2]);
    h1[j][n4 + 3] = sinf(f[3] * a[3]);
  }
  __syncthreads();

  for (int dc = dcg * 3; dc < dcg * 3 + 3; ++dc) {
    for (int p = tid; p < 64 * 64; p += 256) {
      int r = p >> 6, dd = p & 63;
      wch[r][dd] = w_out[r * DIM + dc * 64 + dd];
    }
    __syncthreads();
    // output chunk: 4-wide
    for (int p = tid; p < 528; p += 256) {
      int j = p >> 4, d4 = (p & 15) << 2;
      f32x4 a = {};
      for (int r = 0; r < 64; ++r) {
        f32x4 wv = *(const f32x4*)&wch[r][d4];
        a += h1[j][r] * wv;
      }
      int s = sbase - 1 + j;
      float t = s * (1.0f / 8191.0f);
      unsigned short kq[4];
#pragma unroll
      for (int k = 0; k < 4; ++k) {
        int d = dc * 64 + d4 + k;
        float delta = fabsf(-3.070113457f - 12.280453827f * (d * (1.0f / 767.0f)));
        float val = (s < 0) ? 0.0f : a[k] * expf(-t * delta) * 6.103515625e-05f;
        kq[k] = __builtin_bit_cast(unsigned short, (__bf16)val);
      }
      u32x2 pk = { (uint32_t)kq[0] | ((uint32_t)kq[1] << 16),
                   (uint32_t)kq[2] | ((uint32_t)kq[3] << 16) };
      *(u32x2*)&kv[j][d4] = pk;
    }
    __syncthreads();
    for (int p = tid; p < 32 * 64; p += 256) {
      int j = p >> 6, dd = p & 63;
      int d = dc * 64 + dd;
      int i = 8223 - (sbase + j);
      dupG[(size_t)d * DROW + i] =
          (uint32_t)kv[j + 1][dd] | ((uint32_t)kv[j][dd] << 16);
    }
    if (c == 255 && tid < 64) {
      int d = dc * 64 + tid;
      dupG[(size_t)d * DROW + 31] = ((uint32_t)kv[32][tid] << 16);
    }
    __syncthreads();
  }
}

// ---------------- x (B,L,D) fp32 -> uT[d][b][t] bf16 (vectorized) ---------
__global__ __launch_bounds__(256) void transpose_in_kernel(
    const float* __restrict__ x, unsigned short* __restrict__ uT)
{
  __shared__ unsigned short tile[64][68];
  int b = blockIdx.z;
  int t0 = blockIdx.y * 64;
  int d0 = blockIdx.x * 64;
  int tid = threadIdx.x;

  int ld = tid & 15;
  int tq = tid >> 4;
#pragma unroll
  for (int it = 0; it < 4; ++it) {
    int trow = tq + 16 * it;
    f32x4 xv = *(const f32x4*)&x[((size_t)b * L_SEQ + t0 + trow) * DIM + d0 + 4 * ld];
    unsigned short s0 = __builtin_bit_cast(unsigned short, (__bf16)xv[0]);
    unsigned short s1 = __builtin_bit_cast(unsigned short, (__bf16)xv[1]);
    unsigned short s2 = __builtin_bit_cast(unsigned short, (__bf16)xv[2]);
    unsigned short s3 = __builtin_bit_cast(unsigned short, (__bf16)xv[3]);
    u32x2 pk = { (uint32_t)s0 | ((uint32_t)s1 << 16),
                 (uint32_t)s2 | ((uint32_t)s3 << 16) };
    *(u32x2*)&tile[trow][4 * ld] = pk;
  }
  __syncthreads();

  int l = tid & 63, w = tid >> 6;
  int toct = l & 7;
#pragma unroll
  for (int it = 0; it < 2; ++it) {
    int d = 8 * w + 32 * it + (l >> 3);
    u16x8 o;
#pragma unroll
    for (int c2 = 0; c2 < 8; ++c2) o[c2] = tile[8 * toct + c2][d];
    *(u16x8*)&uT[((size_t)(d0 + d) * 8 + b) * L_SEQ + t0 + 8 * toct] = o;
  }
}

// ---------------- conv: yT[d][b][t] = sum_tau u[b][tau] k[t-tau] ----------
// t-span 1024/block; packed-M (batch, t+16 half); 8 merged tiles/wave.
// A staged via global_load_lds (dbuf/group); A rows padded to 560 B so the
// ds_read_b128 A-reads are bank-conflict-free (140 dwords, 12-step tiling).
#define LOADFRAG(dst, absdw) {                                    \
    int _p = ((absdw) & 2047);                                    \
    u32x4 _u = { buf[_p], buf[_p + 2], buf[_p + 4], buf[_p + 6] };\
    dst = __builtin_bit_cast(bf16x8, _u); }

// A tile: per group, taus [W0+256g-16, W0+256g+256) = 272 taus x 8 rows,
// row = 35 slots x 16B = 560 B (slot 34 = pad). slot s -> b = s/35, e8 = s%35.
#define DSREAD_A(rr, P) (*(const bf16x8*)((P) + abyte + ((rr) << 6)))

typedef __attribute__((address_space(1))) const void g_void;
typedef __attribute__((address_space(3))) void lds_void;

__global__ __launch_bounds__(256) void conv_kernel(
    const uint32_t* __restrict__ dupG,
    const unsigned short* __restrict__ uT,
    unsigned short* __restrict__ yT)
{
  const int d   = blockIdx.y;
  const int T0  = blockIdx.x << 10;      // t-span 1024
  const int tid = threadIdx.x;
  const int lane = tid & 63;
  const int w    = tid >> 6;
  const int m = lane & 15, q = lane >> 4;
  const int h = (lane >> 3) & 1;
  __shared__ uint32_t buf[2080];         // 2048 circular + 32 mirror (dG)
  __shared__ __align__(16) char As0[5120];  // A tile dbuf: 8 rows x 560B
  __shared__ __align__(16) char As1[5120];  // + DMA slack to slot 319

  f32x4 acc[8] = {};
  bf16x8 fr2[8];
  bf16x8 zfr = {};

  float delta = fabsf(-3.070113457f - 12.280453827f * (d * (1.0f / 767.0f)));
  int S = (int)(8191.0f * 3.5065578f / delta);   // decay < 0.03 cutoff
  int tau_start = T0 - S;
  tau_start = (tau_start < 0) ? 0 : (tau_start & ~31);
  int niter = ((T0 + 992 - tau_start) >> 5) + 1;
  niter = (niter + 7) & ~7;              // pad with zero-contribution iters

  const uint32_t* dG = dupG + (size_t)d * DROW;
  const unsigned short* uTd = uT + ((size_t)d << 16);

  int i0 = 7200 + tau_start - T0;        // dG window base (dword idx), >= 32

  // ---- A staging source addresses (35 slots/row) ----
  int s0 = tid;
  int b0 = s0 / 35, r0 = s0 - 35 * b0;
  const char* ga0 = (const char*)uTd + b0 * 16384 + (tau_start - 16 + r0 * 8) * 2;
  int s1 = 256 + lane;
  if (s1 > 279) s1 = 279;                // slots >=280 are pad; clamp source
  int b1 = s1 / 35, r1 = s1 - 35 * b1;
  const char* ga1 = (const char*)uTd + b1 * 16384 + (tau_start - 16 + r1 * 8) * 2;

  const char* Acur = As0;
  const char* Anxt = As1;

  // issue group-0 A stage into As0 (latency overlaps dG prefill)
  __builtin_amdgcn_global_load_lds((g_void*)ga0, (lds_void*)(As0 + (w << 10)), 16, 0, 0);
  if (w == 0)
    __builtin_amdgcn_global_load_lds((g_void*)ga1, (lds_void*)(As0 + 4096), 16, 0, 0);
  ga0 += 512; ga1 += 512;

  // prefill dG window [i0, i0+1280): covers all reads of group 0
  for (int j4 = tid * 4; j4 < 1280; j4 += 1024) {
    int i = i0 + j4;                     // i0 mult of 32 -> 16B aligned
    u32x4 v = *(const u32x4*)&dG[i];
    int pos = i & 2047;
    *(u32x4*)&buf[pos] = v;
    if (pos < 32) *(u32x4*)&buf[2048 + pos] = v;
  }
  __syncthreads();                       // drains A0 DMA + prefill

  // per-lane A read base: byte = 560*b + 32*h + 16*q  (conflict-free tiling)
  const int abyte = 560 * (lane & 7) + (h << 5) + (q << 4);

  int vb = i0 + 1007 - (w << 8) - m + (q << 3);   // abs dword, body 0, tile 0
  int chunk_i = i0 + 1280;

  // prologue: B fragments for tiles j=1..7 of body 0
  LOADFRAG(fr2[7], vb - 32);
  LOADFRAG(fr2[6], vb - 64);
  LOADFRAG(fr2[5], vb - 96);
  LOADFRAG(fr2[4], vb - 128);
  LOADFRAG(fr2[3], vb - 160);
  LOADFRAG(fr2[2], vb - 192);
  LOADFRAG(fr2[1], vb - 224);

  // body-0 afrag + tau<0 kill (global body 0 only)
  bf16x8 pa_c = DSREAD_A(0, Acur);
  if ((tau_start == 0) & (h == 0) & (q < 2)) pa_c = zfr;

#define MFMA_J(rr, j)                                                          \
  acc[j] = __builtin_amdgcn_mfma_f32_16x16x32_bf16(                            \
      afrag, fr2[((rr) - (j)) & 7], acc[j], 0, 0, 0);

#define BODYP(rr) {                                                            \
    LOADFRAG(fr2[(rr) & 7], vb + ((rr) << 5));                                 \
    bf16x8 afrag = pa_c;                                                       \
    pa_c = DSREAD_A((rr) + 1, Acur);                                           \
    MFMA_J(rr, 1) MFMA_J(rr, 2) MFMA_J(rr, 3) MFMA_J(rr, 4)                    \
    MFMA_J(rr, 5) MFMA_J(rr, 6) MFMA_J(rr, 7) MFMA_J(rr, 0)                    \
  }
#define BODYL(rr) {                                                            \
    LOADFRAG(fr2[(rr) & 7], vb + ((rr) << 5));                                 \
    bf16x8 afrag = pa_c;                                                       \
    MFMA_J(rr, 1) MFMA_J(rr, 2) MFMA_J(rr, 3) MFMA_J(rr, 4)                    \
    MFMA_J(rr, 5) MFMA_J(rr, 6) MFMA_J(rr, 7) MFMA_J(rr, 0)                    \
  }

  for (int nn = 0; nn < niter; nn += 8) {
    // issue next group's A stage into Anxt (drained free at the barrier)
    __builtin_amdgcn_global_load_lds((g_void*)ga0, (lds_void*)(Anxt + (w << 10)), 16, 0, 0);
    if (w == 0)
      __builtin_amdgcn_global_load_lds((g_void*)ga1, (lds_void*)(Anxt + 4096), 16, 0, 0);
    ga0 += 512; ga1 += 512;
    // stage next group's dG chunk into registers
    u32x4 stage = {};
    int si4 = chunk_i + (tid << 2);
    if (tid < 64) {
      int iv = (si4 < 8740) ? si4 : 8740;  // clamp into zero tail
      stage = *(const u32x4*)&dG[iv];
    }
    BODYP(0) BODYP(1) BODYP(2) BODYP(3)
    BODYP(4) BODYP(5) BODYP(6) BODYL(7)
    if (tid < 64) {
      int pos = si4 & 2047;
      *(u32x4*)&buf[pos] = stage;
      if (pos < 32) *(u32x4*)&buf[2048 + pos] = stage;
    }
    __syncthreads();
    { const char* t_ = Acur; Acur = Anxt; Anxt = t_; }
    vb += 256; chunk_i += 256;
    pa_c = DSREAD_A(0, Acur);            // body 0 of next group
  }

  // C[row][col]: col = m = t-offset(16), row = q*4+r = (b, h):
  //   y[b][T0 + 256w + 32j + 16h + m]
#pragma unroll
  for (int j = 0; j < 8; ++j) {
    int tb_ = T0 + (w << 8) + (j << 5) + m;
#pragma unroll
    for (int r = 0; r < 4; ++r) {
      int row = q * 4 + r;
      int bb = row & 7;
      int hh = row >> 3;
      yT[((size_t)(d * 8 + bb) << 13) + tb_ + (hh << 4)] =
          __builtin_bit_cast(unsigned short, (__bf16)acc[j][r]);
    }
  }
}

// ---------------- yT[d][b][t] bf16 -> out (B,L,D) fp32 + bias (vector) ----
__global__ __launch_bounds__(256) void transpose_out_kernel(
    const unsigned short* __restrict__ yT, const float* __restrict__ bias,
    float* __restrict__ out)
{
  __shared__ unsigned short tile[64][68];
  int b = blockIdx.z;
  int t0 = blockIdx.y * 64;
  int d0 = blockIdx.x * 64;
  int tid = threadIdx.x;

  int l = tid & 63, w = tid >> 6;
  int toct = l & 7;
#pragma unroll
  for (int it = 0; it < 2; ++it) {
    int d = 8 * w + 32 * it + (l >> 3);
    u16x8 o = *(const u16x8*)&yT[((size_t)(d0 + d) * 8 + b) * L_SEQ + t0 + 8 * toct];
#pragma unroll
    for (int c2 = 0; c2 < 8; ++c2) tile[8 * toct + c2][d] = o[c2];
  }
  __syncthreads();

  int ld = tid & 15;
  int tq = tid >> 4;
  f32x4 bs = *(const f32x4*)&bias[d0 + 4 * ld];
#pragma unroll
  for (int it = 0; it < 4; ++it) {
    int trow = tq + 16 * it;
    u32x2 pk = *(const u32x2*)&tile[trow][4 * ld];
    f32x4 ov;
    ov[0] = (float)__builtin_bit_cast(__bf16, (unsigned short)(pk[0] & 0xffff)) + bs[0];
    ov[1] = (float)__builtin_bit_cast(__bf16, (unsigned short)(pk[0] >> 16))    + bs[1];
    ov[2] = (float)__builtin_bit_cast(__bf16, (unsigned short)(pk[1] & 0xffff)) + bs[2];
    ov[3] = (float)__builtin_bit_cast(__bf16, (unsigned short)(pk[1] >> 16))    + bs[3];
    *(f32x4*)&out[((size_t)b * L_SEQ + t0 + trow) * DIM + d0 + 4 * ld] = ov;
  }
}

extern "C" void kernel_launch(void* const* d_in, const int* in_sizes, int n_in,
                              void* d_out, int out_size, void* d_ws, size_t ws_size,
                              hipStream_t stream)
{
  const float* x       = (const float*)d_in[0];
  const float* w_in    = (const float*)d_in[1];
  const float* b_in    = (const float*)d_in[2];
  const float* freq_in = (const float*)d_in[3];
  const float* w_h0    = (const float*)d_in[4];
  const float* b_h0    = (const float*)d_in[5];
  const float* freq_h0 = (const float*)d_in[6];
  const float* w_h1    = (const float*)d_in[7];
  const float* b_h1    = (const float*)d_in[8];
  const float* freq_h1 = (const float*)d_in[9];
  const float* w_out   = (const float*)d_in[10];
  const float* bias    = (const float*)d_in[11];

  char* ws = (char*)d_ws;
  uint32_t* dupG = (uint32_t*)(ws);
  unsigned short* uT = (unsigned short*)(ws + 26935296);
  unsigned short* yT = (unsigned short*)(ws + 127598592);
  float* out = (float*)d_out;

  hipLaunchKernelGGL(filter_kernel, dim3(256, 4), dim3(256), 0, stream,
                     w_in, b_in, freq_in, w_h0, b_h0, freq_h0,
                     w_h1, b_h1, freq_h1, w_out, dupG);
  hipLaunchKernelGGL(transpose_in_kernel, dim3(12, 128, 8), dim3(256), 0, stream, x, uT);
  hipLaunchKernelGGL(conv_kernel, dim3(8, DIM), dim3(256), 0, stream, dupG, uT, yT);
  hipLaunchKernelGGL(transpose_out_kernel, dim3(12, 128, 8), dim3(256), 0, stream,
                     yT, bias, out);
}